// Round 17
// baseline (72.959 us; speedup 1.0000x reference)
//
#include <hip/hip_runtime.h>
#include <hip/hip_bf16.h>

// ClassBalancedSupConLoss, B=8192, D=128.
// loss_i = -(BASE/t_i)*[P_i - C_i*lse_i]/(C_i+eps)
//   P_i   = invt_i*(e_i.S_{c(i)} - ||e_i||^2)      (fp32 closed form)
//   C_i   = count_{c(i)} - 1
//   lse_i = invt_i*||e_i||^2 + ln(Z_i),  Z_i = sum_j exp2(v_ij - m_i),
//           m_i = invt_i*log2e*||e_i||^2 (fixed reference; exact identity)
// r17: STEP-COUNT MINIMIZATION. Empirical model from r2-r16: k2 time ~
// passes x steps x ~2.2us, almost independent of step content (per-step
// pipe work models to <0.7us). Lever: fewest steps with all blocks
// resident: W=2, NSPLIT=32 -> 1024 blocks (4/CU, all resident), 8 steps.
// This is r12's geometry minus its register spill: lean W=2 (zero-init
// accs + post-MFMA negm add; A read in two 4-chunk halves to cap reg
// liveness ~102), launch_bounds(256,4) (cap 128 > need; r8 lesson),
// dual depth-8 interleaved MFMA chains (r11-proven), DMA staging (r14).
// Ebf/Ebs in MFMA-fragment-tiled order (validated r4+):
//   (r,k) -> tile r>>5, chunk k>>4, lane (r&31)+((k>>3)&1)*32, e k&7.
// 3 dispatches: k0 (single-pass partials), k2 (+aux reduce S/counts,
// zero ticket), k3 (ticket finalize).

#define B_ROWS 8192
#define D_DIM 128
#define NSPLIT 32
#define JRANGE (B_ROWS / NSPLIT)     // 256
#define NSTEPS (JRANGE / 32)         // 8
#define BASE_TEMP 0.07f
#define LOG2E 1.4426950408889634f
#define LN2 0.6931471805599453f
#define FIX_SCALE 1048576.0f         // 2^20

typedef __bf16 bf16x8 __attribute__((ext_vector_type(8)));
typedef __bf16 bf16x4 __attribute__((ext_vector_type(4)));
typedef float floatx16 __attribute__((ext_vector_type(16)));
typedef unsigned long long u64;

__device__ __forceinline__ float class_invtemp(int lbl) {
    return (lbl == 0) ? 12.5f : ((lbl == 1) ? 20.0f : 10.0f);
}

__device__ __forceinline__ u64 fix64(float v) {
    return (u64)(long long)llrintf(v * FIX_SCALE);
}

// direct global->LDS DMA, 16B per lane; lds base must be wave-uniform
__device__ __forceinline__ void load_lds16(const __bf16* g, __bf16* l) {
    __builtin_amdgcn_global_load_lds(
        (const __attribute__((address_space(1))) void*)g,
        (__attribute__((address_space(3))) void*)l,
        16, 0, 0);
}

// ---- K0: single-pass cast->tiled Ebf/Ebs + norms + class partials ----
__global__ __launch_bounds__(256) void k0_prep(
        const float* __restrict__ E, const int* __restrict__ labels,
        __bf16* __restrict__ Ebf, __bf16* __restrict__ Ebs,
        float* __restrict__ nrm,
        float* __restrict__ Spart /*[256][3][128]*/,
        int* __restrict__ cntpart /*[256][4]*/) {
    const int blk = blockIdx.x;          // 256 blocks x 32 rows
    const int tid = threadIdx.x;
    const int row0 = blk * 32;

    __shared__ float4 red[3][256];       // 12 KB class partial reduce
    __shared__ int scnt[3];
    if (tid < 3) scnt[tid] = 0;

    float4 cls0 = {0.f, 0.f, 0.f, 0.f};
    float4 cls1 = {0.f, 0.f, 0.f, 0.f};
    float4 cls2 = {0.f, 0.f, 0.f, 0.f};

    const float4* src = reinterpret_cast<const float4*>(E + (size_t)row0 * D_DIM);
    #pragma unroll
    for (int p = 0; p < 4; ++p) {
        int idx = p * 256 + tid;         // 1024 float4 = 32 rows x 32 k4
        float4 v = src[idx];
        int r = idx >> 5, k4 = idx & 31;
        int R = row0 + r;
        int lab = labels[R];
        float sc = class_invtemp(lab) * LOG2E;
        int T = R >> 5;
        int l = (R & 31) + ((k4 >> 1) & 1) * 32;
        int c = k4 >> 2;
        size_t dst = (size_t)T * 4096 + c * 512 + l * 8 + (k4 & 1) * 4;
        bf16x4 o  = { (__bf16)v.x, (__bf16)v.y, (__bf16)v.z, (__bf16)v.w };
        bf16x4 os = { (__bf16)(v.x * sc), (__bf16)(v.y * sc),
                      (__bf16)(v.z * sc), (__bf16)(v.w * sc) };
        *reinterpret_cast<bf16x4*>(Ebf + dst) = o;
        *reinterpret_cast<bf16x4*>(Ebs + dst) = os;
        // norms: 32 consecutive lanes hold one full row
        float s = v.x * v.x + v.y * v.y + v.z * v.z + v.w * v.w;
        s += __shfl_xor(s, 1);  s += __shfl_xor(s, 2);  s += __shfl_xor(s, 4);
        s += __shfl_xor(s, 8);  s += __shfl_xor(s, 16);
        if ((tid & 31) == 0) nrm[R] = s;
        // class partials in registers (thread owns dims [4*k4, 4*k4+4))
        if (lab == 0) { cls0.x += v.x; cls0.y += v.y; cls0.z += v.z; cls0.w += v.w; }
        else if (lab == 1) { cls1.x += v.x; cls1.y += v.y; cls1.z += v.z; cls1.w += v.w; }
        else { cls2.x += v.x; cls2.y += v.y; cls2.z += v.z; cls2.w += v.w; }
    }
    red[0][tid] = cls0;
    red[1][tid] = cls1;
    red[2][tid] = cls2;
    if (tid < 32) atomicAdd(&scnt[labels[row0 + tid]], 1);   // LDS int: exact
    __syncthreads();

    if (tid < 128) {                     // d = tid; 8 contributors at k4=d>>2
        const int k4 = tid >> 2, comp = tid & 3;
        const float* rf = reinterpret_cast<const float*>(red);
        #pragma unroll
        for (int c = 0; c < 3; ++c) {
            float a = 0.f;
            #pragma unroll
            for (int w = 0; w < 8; ++w)
                a += rf[(c * 256 + k4 + 32 * w) * 4 + comp];
            Spart[((size_t)blk * 3 + c) * 128 + tid] = a;
        }
    }
    if (tid < 3) cntpart[blk * 4 + tid] = scnt[tid];
}

// ---- K2: W=2, NSPLIT=32 (8 steps), DMA-staged A, lean registers ----
// grid (32 itiles, 32 splits) = 1024 blocks = 4/CU all-resident;
// block 256 = 4 waves; wave owns 64 i-cols (two B-tiles).
__global__ __launch_bounds__(256, 4) void k2_stats(
        const __bf16* __restrict__ Ebf, const __bf16* __restrict__ Ebs,
        const int* __restrict__ labels, const float* __restrict__ nrm,
        float* __restrict__ part /*[NSPLIT][B]*/,
        const float* __restrict__ Spart, const int* __restrict__ cntpart,
        float* __restrict__ S /*[3*128]*/, float* __restrict__ counts /*[4]*/,
        u64* __restrict__ lossfix, u64* __restrict__ validfix,
        unsigned int* __restrict__ done) {
    __shared__ __bf16 Ab[2][4096];       // 16 KB A-tile double buffer

    const int tid = threadIdx.x;
    const int lane = tid & 63;
    const int wave = tid >> 6;
    const int itile = blockIdx.x;        // 0..31 (256 i-cols per block)
    const int split = blockIdx.y;        // 0..31
    const int col = lane & 31;
    const int icol0 = itile * 256 + wave * 64 + col;
    const int icol1 = icol0 + 32;

    const float negm0 = -class_invtemp(labels[icol0]) * LOG2E * nrm[icol0];
    const float negm1 = -class_invtemp(labels[icol1]) * LOG2E * nrm[icol1];

    // two B frags (i side), pre-scaled (Ebs), register-resident (32 VGPR)
    const int iT0 = itile * 8 + wave * 2;
    const __bf16* b0 = Ebs + (size_t)iT0 * 4096 + lane * 8;
    bf16x8 Bf0[8], Bf1[8];
    #pragma unroll
    for (int c = 0; c < 8; ++c) {
        Bf0[c] = *reinterpret_cast<const bf16x8*>(b0 + c * 512);
        Bf1[c] = *reinterpret_cast<const bf16x8*>(b0 + 4096 + c * 512);
    }

    // A tiles (j side): Ebf tiles [split*NSTEPS, +NSTEPS), 8 KB each
    const __bf16* abase = Ebf + (size_t)split * NSTEPS * 4096;
    const int woff = wave * 1024 + lane * 8;     // per-lane global offset

    // prologue: DMA tile 0 into buffer 0
    load_lds16(abase + woff,       &Ab[0][wave * 1024]);
    load_lds16(abase + woff + 512, &Ab[0][wave * 1024 + 512]);
    __syncthreads();                              // drains vmcnt(0)

    float Zacc0[4], Zacc1[4];
    #pragma unroll
    for (int q = 0; q < 4; ++q) { Zacc0[q] = 0.f; Zacc1[q] = 0.f; }

    for (int s = 0; s < NSTEPS; ++s) {
        // issue next-tile DMA FIRST (fire-and-forget; lands before barrier)
        if (s + 1 < NSTEPS) {
            const __bf16* g = abase + (size_t)(s + 1) * 4096 + woff;
            __bf16* l = &Ab[(s + 1) & 1][wave * 1024];
            load_lds16(g, l);
            load_lds16(g + 512, l + 512);
        }

        const __bf16* abuf = &Ab[s & 1][0];
        floatx16 a0, a1;                 // dual depth-8 chains (ILP=2)
        #pragma unroll
        for (int r = 0; r < 16; ++r) { a0[r] = 0.f; a1[r] = 0.f; }

        // half 1: K chunks 0..3 (A liveness capped at 16 VGPR)
        {
            bf16x8 A[4];
            #pragma unroll
            for (int c = 0; c < 4; ++c)
                A[c] = *reinterpret_cast<const bf16x8*>(abuf + c * 512 + lane * 8);
            #pragma unroll
            for (int c = 0; c < 4; ++c) {
                a0 = __builtin_amdgcn_mfma_f32_32x32x16_bf16(A[c], Bf0[c], a0, 0, 0, 0);
                a1 = __builtin_amdgcn_mfma_f32_32x32x16_bf16(A[c], Bf1[c], a1, 0, 0, 0);
            }
        }
        // half 2: K chunks 4..7
        {
            bf16x8 A[4];
            #pragma unroll
            for (int c = 0; c < 4; ++c)
                A[c] = *reinterpret_cast<const bf16x8*>(abuf + (c + 4) * 512 + lane * 8);
            #pragma unroll
            for (int c = 0; c < 4; ++c) {
                a0 = __builtin_amdgcn_mfma_f32_32x32x16_bf16(A[c], Bf0[c + 4], a0, 0, 0, 0);
                a1 = __builtin_amdgcn_mfma_f32_32x32x16_bf16(A[c], Bf1[c + 4], a1, 0, 0, 0);
            }
        }

        #pragma unroll
        for (int q = 0; q < 4; ++q) {
            Zacc0[q] += (__builtin_amdgcn_exp2f(a0[4 * q]     + negm0)
                       + __builtin_amdgcn_exp2f(a0[4 * q + 1] + negm0))
                      + (__builtin_amdgcn_exp2f(a0[4 * q + 2] + negm0)
                       + __builtin_amdgcn_exp2f(a0[4 * q + 3] + negm0));
            Zacc1[q] += (__builtin_amdgcn_exp2f(a1[4 * q]     + negm1)
                       + __builtin_amdgcn_exp2f(a1[4 * q + 1] + negm1))
                      + (__builtin_amdgcn_exp2f(a1[4 * q + 2] + negm1)
                       + __builtin_amdgcn_exp2f(a1[4 * q + 3] + negm1));
        }

        // one barrier per step (compiler folds vmcnt/lgkm drain into it)
        __syncthreads();
    }

    float Zt0 = (Zacc0[0] + Zacc0[1]) + (Zacc0[2] + Zacc0[3]);
    float Zt1 = (Zacc1[0] + Zacc1[1]) + (Zacc1[2] + Zacc1[3]);
    Zt0 += __shfl_xor(Zt0, 32);          // lanes l, l+32 hold same i-col
    Zt1 += __shfl_xor(Zt1, 32);
    if (lane < 32) {
        part[(size_t)split * B_ROWS + icol0] = Zt0;
        part[(size_t)split * B_ROWS + icol1] = Zt1;
    }

    // ---- aux (ordered before k3 by stream): S, counts, ticket zero ----
    if (split == 0) {
        if (itile < 3 && tid < 128) {
            float a = 0.f;
            #pragma unroll 8
            for (int g = 0; g < 256; ++g)
                a += Spart[((size_t)g * 3 + itile) * 128 + tid];
            S[itile * 128 + tid] = a;
        } else if (itile == 3 && tid < 3) {
            int a = 0;
            #pragma unroll 8
            for (int g = 0; g < 256; ++g) a += cntpart[g * 4 + tid];
            counts[tid] = (float)a;
        } else if (itile == 4 && tid == 0) {
            *lossfix = 0ull;
            *validfix = 0ull;
            *done = 0u;
        }
    }
}

// ---- K3: per-row loss (8 thr/row), fixed-point accumulate + ticket ----
__global__ __launch_bounds__(256) void k3_rowloss(
        const float* __restrict__ E, const int* __restrict__ labels,
        const float* __restrict__ S, const float* __restrict__ counts,
        const float* __restrict__ nrm, const float* __restrict__ part,
        u64* __restrict__ lossfix, u64* __restrict__ validfix,
        unsigned int* __restrict__ done, float* __restrict__ out) {
    __shared__ float sS[384];
    const int tid = threadIdx.x;
    if (tid < 128) {
        sS[tid]       = S[tid];
        sS[128 + tid] = S[128 + tid];
        sS[256 + tid] = S[256 + tid];
    }
    __syncthreads();

    const int r = tid >> 3, g = tid & 7;       // 32 rows/block, 8 thr/row
    const int i = blockIdx.x * 32 + r;
    const int lab = labels[i];
    const float invt = class_invtemp(lab);

    const float4* er = reinterpret_cast<const float4*>(E + (size_t)i * D_DIM);
    const float4* sr = reinterpret_cast<const float4*>(&sS[lab * 128]);
    float dotS = 0.f;
    #pragma unroll
    for (int q = 0; q < 4; ++q) {
        float4 v = er[g * 4 + q];
        float4 s = sr[g * 4 + q];
        dotS += v.x * s.x + v.y * s.y + v.z * s.z + v.w * s.w;
    }
    float Zp = 0.f;
    #pragma unroll
    for (int p = 0; p < NSPLIT / 8; ++p)
        Zp += part[(size_t)(g + p * 8) * B_ROWS + i];

    #pragma unroll
    for (int off = 1; off < 8; off <<= 1) {
        dotS += __shfl_xor(dotS, off);
        Zp   += __shfl_xor(Zp, off);
    }

    float loss = 0.f;
    int valid = 0;
    if (g == 0) {
        const float nr = nrm[i];
        const float C = counts[lab] - 1.0f;
        const float lse = invt * nr + LN2 * __builtin_amdgcn_logf(Zp);
        const float P_nat = invt * (dotS - nr);
        if (C > 0.f) {
            loss = -(BASE_TEMP * invt) * (P_nat - C * lse) / (C + 1e-8f);
            valid = 1;
        }
    }
    loss += __shfl_down(loss, 8);   valid += __shfl_down(valid, 8);
    loss += __shfl_down(loss, 16);  valid += __shfl_down(valid, 16);
    loss += __shfl_down(loss, 32);  valid += __shfl_down(valid, 32);

    __shared__ float rl[4];
    __shared__ int rv[4];
    if ((tid & 63) == 0) { rl[tid >> 6] = loss; rv[tid >> 6] = valid; }
    __syncthreads();
    if (tid == 0) {
        float bt = (rl[0] + rl[1]) + (rl[2] + rl[3]);
        int bv = (rv[0] + rv[1]) + (rv[2] + rv[3]);
        atomicAdd(lossfix, fix64(bt));
        atomicAdd(validfix, (u64)bv);
        __threadfence();
        unsigned int t = atomicAdd(done, 1u);
        if (t == gridDim.x - 1) {     // last block finalizes (deterministic)
            u64 L = atomicAdd(lossfix, 0ull);
            u64 V = atomicAdd(validfix, 0ull);
            double T = (double)(long long)L * (1.0 / (double)FIX_SCALE);
            double N = (double)(long long)V;
            out[0] = (N > 0.0) ? (float)(T / fmax(N, 1.0)) : 0.f;
        }
    }
}

extern "C" void kernel_launch(void* const* d_in, const int* in_sizes, int n_in,
                              void* d_out, int out_size, void* d_ws, size_t ws_size,
                              hipStream_t stream) {
    const float* E = (const float*)d_in[0];
    const int* labels = (const int*)d_in[1];
    float* out = (float*)d_out;
    char* ws = (char*)d_ws;

    // workspace layout (~6 MB)
    const size_t OFF_EBF   = 0;                        // 2 MB tiled bf16
    const size_t OFF_EBS   = (size_t)2 << 20;          // 2 MB tiled bf16 (scaled)
    const size_t OFF_NRM   = (size_t)4 << 20;          // 32 KB row norms
    const size_t OFF_SPART = OFF_NRM + 32768;          // 384 KB
    const size_t OFF_CNTP  = OFF_SPART + 393216;       // 4 KB
    const size_t OFF_S     = OFF_CNTP + 4096;          // 1.5 KB
    const size_t OFF_MISC  = OFF_S + 2048;             // counts + ticket
    const size_t OFF_PART  = (size_t)5 << 20;          // 1 MB (32 x 8192 f32)

    __bf16* Ebf = (__bf16*)(ws + OFF_EBF);
    __bf16* Ebs = (__bf16*)(ws + OFF_EBS);
    float* nrm = (float*)(ws + OFF_NRM);
    float* Spart = (float*)(ws + OFF_SPART);
    int* cntpart = (int*)(ws + OFF_CNTP);
    float* S = (float*)(ws + OFF_S);
    float* counts = (float*)(ws + OFF_MISC);           // 4 f32
    u64* lossfix = (u64*)(ws + OFF_MISC + 16);
    u64* validfix = (u64*)(ws + OFF_MISC + 24);
    unsigned int* done = (unsigned int*)(ws + OFF_MISC + 32);
    float* part = (float*)(ws + OFF_PART);

    k0_prep<<<256, 256, 0, stream>>>(E, labels, Ebf, Ebs, nrm, Spart, cntpart);
    k2_stats<<<dim3(32, NSPLIT), 256, 0, stream>>>(
        Ebf, Ebs, labels, nrm, part, Spart, cntpart, S, counts,
        lossfix, validfix, done);
    k3_rowloss<<<256, 256, 0, stream>>>(E, labels, S, counts, nrm, part,
                                        lossfix, validfix, done, out);
}

// Round 18
// 47.616 us; speedup vs baseline: 1.5323x; 1.5323x over previous
//
#include <hip/hip_runtime.h>
#include <hip/hip_bf16.h>

// ClassBalancedSupConLoss, B=8192, D=128.
// loss_i = -(BASE/t_i)*[P_i - C_i*lse_i]/(C_i+eps)
//   P_i   = invt_i*(e_i.S_{c(i)} - ||e_i||^2)      (fp32 closed form)
//   C_i   = count_{c(i)} - 1
//   lse_i = invt_i*||e_i||^2 + ln(Z_i),  Z_i = sum_j exp2(v_ij - m_i),
//           m_i = invt_i*log2e*||e_i||^2 (fixed reference; exact identity)
// r18 = r16 core + T3/T4 (counted vmcnt, raw barrier, triple buffer).
// Diagnosis: per-step cost ~2.2us >> pipe work ~0.7us because
// __syncthreads() lowers to s_waitcnt vmcnt(0) lgkmcnt(0) + s_barrier,
// draining the in-flight global_load_lds DMA (~500-900cyc) EVERY step.
// Fix (guide T3/T4): per step [vmcnt(2)] [raw s_barrier] [sched_barrier]
// [issue DMA s+2] [ds_read tile s] [compute]. DMA latency spans 2 steps;
// never drain to 0 in the loop (last step peels to vmcnt(0)).
// Hazards: read-after-DMA covered by per-wave vmcnt(2)+barrier (tile s
// issued 2 steps ago -> oldest-2 rule); WAR on buf[(s+2)%3]=buf[(s-1)%3]
// covered because issue is AFTER the barrier all waves crossed.
// LESSONS: r8/r17 NEVER pass min-waves to k2 (VGPR cap -> spill);
// r12 no persistent acc; r10 prefetch load-bearing; r15 no tail fusion.
// Ebf/Ebs in MFMA-fragment-tiled order (validated r4+):
//   (r,k) -> tile r>>5, chunk k>>4, lane (r&31)+((k>>3)&1)*32, e k&7.

#define B_ROWS 8192
#define D_DIM 128
#define NSPLIT 16
#define JRANGE (B_ROWS / NSPLIT)     // 512
#define NSTEPS (JRANGE / 32)         // 16
#define BASE_TEMP 0.07f
#define LOG2E 1.4426950408889634f
#define LN2 0.6931471805599453f
#define FIX_SCALE 1048576.0f         // 2^20

typedef __bf16 bf16x8 __attribute__((ext_vector_type(8)));
typedef __bf16 bf16x4 __attribute__((ext_vector_type(4)));
typedef float floatx16 __attribute__((ext_vector_type(16)));
typedef unsigned long long u64;

__device__ __forceinline__ float class_invtemp(int lbl) {
    return (lbl == 0) ? 12.5f : ((lbl == 1) ? 20.0f : 10.0f);
}

__device__ __forceinline__ u64 fix64(float v) {
    return (u64)(long long)llrintf(v * FIX_SCALE);
}

// direct global->LDS DMA, 16B per lane; lds base must be wave-uniform
__device__ __forceinline__ void load_lds16(const __bf16* g, __bf16* l) {
    __builtin_amdgcn_global_load_lds(
        (const __attribute__((address_space(1))) void*)g,
        (__attribute__((address_space(3))) void*)l,
        16, 0, 0);
}

// ---- K0: single-pass cast->tiled Ebf/Ebs + norms + class partials ----
__global__ __launch_bounds__(256) void k0_prep(
        const float* __restrict__ E, const int* __restrict__ labels,
        __bf16* __restrict__ Ebf, __bf16* __restrict__ Ebs,
        float* __restrict__ nrm,
        float* __restrict__ Spart /*[256][3][128]*/,
        int* __restrict__ cntpart /*[256][4]*/) {
    const int blk = blockIdx.x;          // 256 blocks x 32 rows
    const int tid = threadIdx.x;
    const int row0 = blk * 32;

    __shared__ float4 red[3][256];       // 12 KB class partial reduce
    __shared__ int scnt[3];
    if (tid < 3) scnt[tid] = 0;

    float4 cls0 = {0.f, 0.f, 0.f, 0.f};
    float4 cls1 = {0.f, 0.f, 0.f, 0.f};
    float4 cls2 = {0.f, 0.f, 0.f, 0.f};

    const float4* src = reinterpret_cast<const float4*>(E + (size_t)row0 * D_DIM);
    #pragma unroll
    for (int p = 0; p < 4; ++p) {
        int idx = p * 256 + tid;         // 1024 float4 = 32 rows x 32 k4
        float4 v = src[idx];
        int r = idx >> 5, k4 = idx & 31;
        int R = row0 + r;
        int lab = labels[R];
        float sc = class_invtemp(lab) * LOG2E;
        int T = R >> 5;
        int l = (R & 31) + ((k4 >> 1) & 1) * 32;
        int c = k4 >> 2;
        size_t dst = (size_t)T * 4096 + c * 512 + l * 8 + (k4 & 1) * 4;
        bf16x4 o  = { (__bf16)v.x, (__bf16)v.y, (__bf16)v.z, (__bf16)v.w };
        bf16x4 os = { (__bf16)(v.x * sc), (__bf16)(v.y * sc),
                      (__bf16)(v.z * sc), (__bf16)(v.w * sc) };
        *reinterpret_cast<bf16x4*>(Ebf + dst) = o;
        *reinterpret_cast<bf16x4*>(Ebs + dst) = os;
        // norms: 32 consecutive lanes hold one full row
        float s = v.x * v.x + v.y * v.y + v.z * v.z + v.w * v.w;
        s += __shfl_xor(s, 1);  s += __shfl_xor(s, 2);  s += __shfl_xor(s, 4);
        s += __shfl_xor(s, 8);  s += __shfl_xor(s, 16);
        if ((tid & 31) == 0) nrm[R] = s;
        // class partials in registers (thread owns dims [4*k4, 4*k4+4))
        if (lab == 0) { cls0.x += v.x; cls0.y += v.y; cls0.z += v.z; cls0.w += v.w; }
        else if (lab == 1) { cls1.x += v.x; cls1.y += v.y; cls1.z += v.z; cls1.w += v.w; }
        else { cls2.x += v.x; cls2.y += v.y; cls2.z += v.z; cls2.w += v.w; }
    }
    red[0][tid] = cls0;
    red[1][tid] = cls1;
    red[2][tid] = cls2;
    if (tid < 32) atomicAdd(&scnt[labels[row0 + tid]], 1);   // LDS int: exact
    __syncthreads();

    if (tid < 128) {                     // d = tid; 8 contributors at k4=d>>2
        const int k4 = tid >> 2, comp = tid & 3;
        const float* rf = reinterpret_cast<const float*>(red);
        #pragma unroll
        for (int c = 0; c < 3; ++c) {
            float a = 0.f;
            #pragma unroll
            for (int w = 0; w < 8; ++w)
                a += rf[(c * 256 + k4 + 32 * w) * 4 + comp];
            Spart[((size_t)blk * 3 + c) * 128 + tid] = a;
        }
    }
    if (tid < 3) cntpart[blk * 4 + tid] = scnt[tid];
}

// ---- K2: triple-buffered DMA, counted vmcnt, raw barriers ----
// grid (64 itiles, NSPLIT); block 256 = 4 waves; wave owns 32 i-cols.
__global__ __launch_bounds__(256) void k2_stats(
        const __bf16* __restrict__ Ebf, const __bf16* __restrict__ Ebs,
        const int* __restrict__ labels, const float* __restrict__ nrm,
        float* __restrict__ part /*[NSPLIT][B]*/,
        const float* __restrict__ Spart, const int* __restrict__ cntpart,
        float* __restrict__ S /*[3*128]*/, float* __restrict__ counts /*[4]*/,
        u64* __restrict__ lossfix, u64* __restrict__ validfix,
        unsigned int* __restrict__ done) {
    __shared__ __bf16 Ab[3][4096];       // 24 KB A-tile TRIPLE buffer

    const int tid = threadIdx.x;
    const int lane = tid & 63;
    const int wave = tid >> 6;
    const int itile = blockIdx.x;        // 0..63 (128 i-cols per block)
    const int split = blockIdx.y;        // 0..NSPLIT-1
    const int col = lane & 31;
    const int icol = itile * 128 + wave * 32 + col;

    const float negm = -class_invtemp(labels[icol]) * LOG2E * nrm[icol];

    // B frag (i side), pre-scaled (Ebs), register-resident (32 VGPR);
    // loaded BEFORE any DMA so the compiler's wait for Bf drains nothing.
    const int iT = itile * 4 + wave;
    const __bf16* bbase = Ebs + (size_t)iT * 4096 + lane * 8;
    bf16x8 Bf[8];
    #pragma unroll
    for (int c = 0; c < 8; ++c)
        Bf[c] = *reinterpret_cast<const bf16x8*>(bbase + c * 512);

    // persistent C-in vector: a0 chain starts at -m with no per-step movs
    floatx16 init0;
    #pragma unroll
    for (int r = 0; r < 16; ++r) init0[r] = negm;

    // A tiles (j side): Ebf tiles [split*NSTEPS, +NSTEPS), 8 KB each
    const __bf16* abase = Ebf + (size_t)split * NSTEPS * 4096;
    const int woff = wave * 1024 + lane * 8;     // per-lane global offset

    // prologue: DMA tiles 0 and 1 (4 ops in flight)
    load_lds16(abase + woff,              &Ab[0][wave * 1024]);
    load_lds16(abase + woff + 512,        &Ab[0][wave * 1024 + 512]);
    load_lds16(abase + 4096 + woff,       &Ab[1][wave * 1024]);
    load_lds16(abase + 4096 + woff + 512, &Ab[1][wave * 1024 + 512]);

    float Zacc[4];
    #pragma unroll
    for (int q = 0; q < 4; ++q) Zacc[q] = 0.f;

    #pragma unroll 1
    for (int s = 0; s < NSTEPS; ++s) {
        // counted wait: tile s's 2 ops are the oldest; allow tile s+1's
        // (and not-yet-issued s+2's) to stay in flight. Never 0 mid-loop.
        if (s < NSTEPS - 1) {
            asm volatile("s_waitcnt vmcnt(2)" ::: "memory");
        } else {
            asm volatile("s_waitcnt vmcnt(0)" ::: "memory");
        }
        __builtin_amdgcn_s_barrier();            // raw: no implicit drain
        __builtin_amdgcn_sched_barrier(0);       // pin ds_reads below

        // issue DMA for tile s+2 AFTER the barrier (WAR-safe: its buffer
        // was last read at step s-1, finished before this barrier)
        if (s + 2 < NSTEPS) {
            const __bf16* g = abase + (size_t)(s + 2) * 4096 + woff;
            __bf16* l = &Ab[(s + 2) % 3][wave * 1024];
            load_lds16(g, l);
            load_lds16(g + 512, l + 512);
        }

        // ds_read current A fragments (conflict-free: lane-contiguous 16B)
        const __bf16* abuf = &Ab[s % 3][0];
        bf16x8 A[8];
        #pragma unroll
        for (int c = 0; c < 8; ++c)
            A[c] = *reinterpret_cast<const bf16x8*>(abuf + c * 512 + lane * 8);

        // dual K-split chains: a0 = -m + dot(k<64), a1 = dot(k>=64)
        floatx16 a1;
        #pragma unroll
        for (int r = 0; r < 16; ++r) a1[r] = 0.f;
        floatx16 a0 = __builtin_amdgcn_mfma_f32_32x32x16_bf16(A[0], Bf[0], init0, 0, 0, 0);
        a1 = __builtin_amdgcn_mfma_f32_32x32x16_bf16(A[4], Bf[4], a1, 0, 0, 0);
        a0 = __builtin_amdgcn_mfma_f32_32x32x16_bf16(A[1], Bf[1], a0, 0, 0, 0);
        a1 = __builtin_amdgcn_mfma_f32_32x32x16_bf16(A[5], Bf[5], a1, 0, 0, 0);
        a0 = __builtin_amdgcn_mfma_f32_32x32x16_bf16(A[2], Bf[2], a0, 0, 0, 0);
        a1 = __builtin_amdgcn_mfma_f32_32x32x16_bf16(A[6], Bf[6], a1, 0, 0, 0);
        a0 = __builtin_amdgcn_mfma_f32_32x32x16_bf16(A[3], Bf[3], a0, 0, 0, 0);
        a1 = __builtin_amdgcn_mfma_f32_32x32x16_bf16(A[7], Bf[7], a1, 0, 0, 0);

        #pragma unroll
        for (int q = 0; q < 4; ++q) {
            Zacc[q] += (__builtin_amdgcn_exp2f(a0[4 * q]     + a1[4 * q])
                      + __builtin_amdgcn_exp2f(a0[4 * q + 1] + a1[4 * q + 1]))
                     + (__builtin_amdgcn_exp2f(a0[4 * q + 2] + a1[4 * q + 2])
                      + __builtin_amdgcn_exp2f(a0[4 * q + 3] + a1[4 * q + 3]));
        }
        // no trailing barrier: triple buffer means nothing written this
        // step is read by another wave before the NEXT step's barrier
    }

    float Zt = (Zacc[0] + Zacc[1]) + (Zacc[2] + Zacc[3]);
    Zt += __shfl_xor(Zt, 32);            // lanes l, l+32 hold same i-col
    if (lane < 32)
        part[(size_t)split * B_ROWS + icol] = Zt;

    // ---- aux (ordered before k3 by stream): S, counts, ticket zero ----
    if (split == 0) {
        if (itile < 3 && tid < 128) {
            float a = 0.f;
            #pragma unroll 8
            for (int g = 0; g < 256; ++g)
                a += Spart[((size_t)g * 3 + itile) * 128 + tid];
            S[itile * 128 + tid] = a;
        } else if (itile == 3 && tid < 3) {
            int a = 0;
            #pragma unroll 8
            for (int g = 0; g < 256; ++g) a += cntpart[g * 4 + tid];
            counts[tid] = (float)a;
        } else if (itile == 4 && tid == 0) {
            *lossfix = 0ull;
            *validfix = 0ull;
            *done = 0u;
        }
    }
}

// ---- K3: per-row loss (8 thr/row), fixed-point accumulate + ticket ----
__global__ __launch_bounds__(256) void k3_rowloss(
        const float* __restrict__ E, const int* __restrict__ labels,
        const float* __restrict__ S, const float* __restrict__ counts,
        const float* __restrict__ nrm, const float* __restrict__ part,
        u64* __restrict__ lossfix, u64* __restrict__ validfix,
        unsigned int* __restrict__ done, float* __restrict__ out) {
    __shared__ float sS[384];
    const int tid = threadIdx.x;
    if (tid < 128) {
        sS[tid]       = S[tid];
        sS[128 + tid] = S[128 + tid];
        sS[256 + tid] = S[256 + tid];
    }
    __syncthreads();

    const int r = tid >> 3, g = tid & 7;       // 32 rows/block, 8 thr/row
    const int i = blockIdx.x * 32 + r;
    const int lab = labels[i];
    const float invt = class_invtemp(lab);

    const float4* er = reinterpret_cast<const float4*>(E + (size_t)i * D_DIM);
    const float4* sr = reinterpret_cast<const float4*>(&sS[lab * 128]);
    float dotS = 0.f;
    #pragma unroll
    for (int q = 0; q < 4; ++q) {
        float4 v = er[g * 4 + q];
        float4 s = sr[g * 4 + q];
        dotS += v.x * s.x + v.y * s.y + v.z * s.z + v.w * s.w;
    }
    float Zp = 0.f;
    #pragma unroll
    for (int p = 0; p < NSPLIT / 8; ++p)
        Zp += part[(size_t)(g + p * 8) * B_ROWS + i];

    #pragma unroll
    for (int off = 1; off < 8; off <<= 1) {
        dotS += __shfl_xor(dotS, off);
        Zp   += __shfl_xor(Zp, off);
    }

    float loss = 0.f;
    int valid = 0;
    if (g == 0) {
        const float nr = nrm[i];
        const float C = counts[lab] - 1.0f;
        const float lse = invt * nr + LN2 * __builtin_amdgcn_logf(Zp);
        const float P_nat = invt * (dotS - nr);
        if (C > 0.f) {
            loss = -(BASE_TEMP * invt) * (P_nat - C * lse) / (C + 1e-8f);
            valid = 1;
        }
    }
    loss += __shfl_down(loss, 8);   valid += __shfl_down(valid, 8);
    loss += __shfl_down(loss, 16);  valid += __shfl_down(valid, 16);
    loss += __shfl_down(loss, 32);  valid += __shfl_down(valid, 32);

    __shared__ float rl[4];
    __shared__ int rv[4];
    if ((tid & 63) == 0) { rl[tid >> 6] = loss; rv[tid >> 6] = valid; }
    __syncthreads();
    if (tid == 0) {
        float bt = (rl[0] + rl[1]) + (rl[2] + rl[3]);
        int bv = (rv[0] + rv[1]) + (rv[2] + rv[3]);
        atomicAdd(lossfix, fix64(bt));
        atomicAdd(validfix, (u64)bv);
        __threadfence();
        unsigned int t = atomicAdd(done, 1u);
        if (t == gridDim.x - 1) {     // last block finalizes (deterministic)
            u64 L = atomicAdd(lossfix, 0ull);
            u64 V = atomicAdd(validfix, 0ull);
            double T = (double)(long long)L * (1.0 / (double)FIX_SCALE);
            double N = (double)(long long)V;
            out[0] = (N > 0.0) ? (float)(T / fmax(N, 1.0)) : 0.f;
        }
    }
}

extern "C" void kernel_launch(void* const* d_in, const int* in_sizes, int n_in,
                              void* d_out, int out_size, void* d_ws, size_t ws_size,
                              hipStream_t stream) {
    const float* E = (const float*)d_in[0];
    const int* labels = (const int*)d_in[1];
    float* out = (float*)d_out;
    char* ws = (char*)d_ws;

    // workspace layout (~6 MB)
    const size_t OFF_EBF   = 0;                        // 2 MB tiled bf16
    const size_t OFF_EBS   = (size_t)2 << 20;          // 2 MB tiled bf16 (scaled)
    const size_t OFF_NRM   = (size_t)4 << 20;          // 32 KB row norms
    const size_t OFF_SPART = OFF_NRM + 32768;          // 384 KB
    const size_t OFF_CNTP  = OFF_SPART + 393216;       // 4 KB
    const size_t OFF_S     = OFF_CNTP + 4096;          // 1.5 KB
    const size_t OFF_MISC  = OFF_S + 2048;             // counts + ticket
    const size_t OFF_PART  = (size_t)5 << 20;          // 512 KB (16 x 8192 f32)

    __bf16* Ebf = (__bf16*)(ws + OFF_EBF);
    __bf16* Ebs = (__bf16*)(ws + OFF_EBS);
    float* nrm = (float*)(ws + OFF_NRM);
    float* Spart = (float*)(ws + OFF_SPART);
    int* cntpart = (int*)(ws + OFF_CNTP);
    float* S = (float*)(ws + OFF_S);
    float* counts = (float*)(ws + OFF_MISC);           // 4 f32
    u64* lossfix = (u64*)(ws + OFF_MISC + 16);
    u64* validfix = (u64*)(ws + OFF_MISC + 24);
    unsigned int* done = (unsigned int*)(ws + OFF_MISC + 32);
    float* part = (float*)(ws + OFF_PART);

    k0_prep<<<256, 256, 0, stream>>>(E, labels, Ebf, Ebs, nrm, Spart, cntpart);
    k2_stats<<<dim3(64, NSPLIT), 256, 0, stream>>>(
        Ebf, Ebs, labels, nrm, part, Spart, cntpart, S, counts,
        lossfix, validfix, done);
    k3_rowloss<<<256, 256, 0, stream>>>(E, labels, S, counts, nrm, part,
                                        lossfix, validfix, done, out);
}

// Round 19
// 47.099 us; speedup vs baseline: 1.5491x; 1.0110x over previous
//
#include <hip/hip_runtime.h>
#include <hip/hip_bf16.h>

// ClassBalancedSupConLoss, B=8192, D=128.
// loss_i = -(BASE/t_i)*[P_i - C_i*lse_i]/(C_i+eps)
//   P_i   = invt_i*(e_i.S_{c(i)} - ||e_i||^2)      (fp32 closed form)
//   C_i   = count_{c(i)} - 1
//   lse_i = invt_i*||e_i||^2 + ln(Z_i),  Z_i = sum_j exp2(v_ij - m_i),
//           m_i = invt_i*log2e*||e_i||^2 (fixed reference; exact identity)
// r19 = r18 + CROSS-TILE SOFTWARE PIPELINE (deferred exp):
//   tile t: [vmcnt(2)] [s_barrier] [DMA t+2] [ds_read t] [setprio(1)
//   8-MFMA chain -> cur] [setprio(0)] [exp2 block of tile t-1's prev acc]
// The exp/VALU work of t-1 has no dependency on tile t's MFMAs -> issues
// under the matrix pipe (m114 dual-pipe overlap). Even/odd acc generations
// are NAMED accA/accB (rule #20: no runtime-indexed acc arrays; r12 spill
// lesson: only 2x16 acc regs, total ~120 VGPR). setprio now has role
// diversity to arbitrate (T5 pays only with phase-split, m218b).
// Single MFMA chain per tile: its latency hides under prev-exp instead of
// stalling (r6's ILP penalty neutralized by the pipeline).
// LESSONS kept: r8/r17 no min-waves launch_bounds; r14 DMA staging;
// r18 counted vmcnt(2) + raw barrier + triple buffer (hazards unchanged).
// Ebf/Ebs in MFMA-fragment-tiled order (validated r4+):
//   (r,k) -> tile r>>5, chunk k>>4, lane (r&31)+((k>>3)&1)*32, e k&7.

#define B_ROWS 8192
#define D_DIM 128
#define NSPLIT 16
#define JRANGE (B_ROWS / NSPLIT)     // 512
#define NSTEPS (JRANGE / 32)         // 16
#define BASE_TEMP 0.07f
#define LOG2E 1.4426950408889634f
#define LN2 0.6931471805599453f
#define FIX_SCALE 1048576.0f         // 2^20

typedef __bf16 bf16x8 __attribute__((ext_vector_type(8)));
typedef __bf16 bf16x4 __attribute__((ext_vector_type(4)));
typedef float floatx16 __attribute__((ext_vector_type(16)));
typedef unsigned long long u64;

__device__ __forceinline__ float class_invtemp(int lbl) {
    return (lbl == 0) ? 12.5f : ((lbl == 1) ? 20.0f : 10.0f);
}

__device__ __forceinline__ u64 fix64(float v) {
    return (u64)(long long)llrintf(v * FIX_SCALE);
}

// direct global->LDS DMA, 16B per lane; lds base must be wave-uniform
__device__ __forceinline__ void load_lds16(const __bf16* g, __bf16* l) {
    __builtin_amdgcn_global_load_lds(
        (const __attribute__((address_space(1))) void*)g,
        (__attribute__((address_space(3))) void*)l,
        16, 0, 0);
}

// ---- K0: single-pass cast->tiled Ebf/Ebs + norms + class partials ----
__global__ __launch_bounds__(256) void k0_prep(
        const float* __restrict__ E, const int* __restrict__ labels,
        __bf16* __restrict__ Ebf, __bf16* __restrict__ Ebs,
        float* __restrict__ nrm,
        float* __restrict__ Spart /*[256][3][128]*/,
        int* __restrict__ cntpart /*[256][4]*/) {
    const int blk = blockIdx.x;          // 256 blocks x 32 rows
    const int tid = threadIdx.x;
    const int row0 = blk * 32;

    __shared__ float4 red[3][256];       // 12 KB class partial reduce
    __shared__ int scnt[3];
    if (tid < 3) scnt[tid] = 0;

    float4 cls0 = {0.f, 0.f, 0.f, 0.f};
    float4 cls1 = {0.f, 0.f, 0.f, 0.f};
    float4 cls2 = {0.f, 0.f, 0.f, 0.f};

    const float4* src = reinterpret_cast<const float4*>(E + (size_t)row0 * D_DIM);
    #pragma unroll
    for (int p = 0; p < 4; ++p) {
        int idx = p * 256 + tid;         // 1024 float4 = 32 rows x 32 k4
        float4 v = src[idx];
        int r = idx >> 5, k4 = idx & 31;
        int R = row0 + r;
        int lab = labels[R];
        float sc = class_invtemp(lab) * LOG2E;
        int T = R >> 5;
        int l = (R & 31) + ((k4 >> 1) & 1) * 32;
        int c = k4 >> 2;
        size_t dst = (size_t)T * 4096 + c * 512 + l * 8 + (k4 & 1) * 4;
        bf16x4 o  = { (__bf16)v.x, (__bf16)v.y, (__bf16)v.z, (__bf16)v.w };
        bf16x4 os = { (__bf16)(v.x * sc), (__bf16)(v.y * sc),
                      (__bf16)(v.z * sc), (__bf16)(v.w * sc) };
        *reinterpret_cast<bf16x4*>(Ebf + dst) = o;
        *reinterpret_cast<bf16x4*>(Ebs + dst) = os;
        // norms: 32 consecutive lanes hold one full row
        float s = v.x * v.x + v.y * v.y + v.z * v.z + v.w * v.w;
        s += __shfl_xor(s, 1);  s += __shfl_xor(s, 2);  s += __shfl_xor(s, 4);
        s += __shfl_xor(s, 8);  s += __shfl_xor(s, 16);
        if ((tid & 31) == 0) nrm[R] = s;
        // class partials in registers (thread owns dims [4*k4, 4*k4+4))
        if (lab == 0) { cls0.x += v.x; cls0.y += v.y; cls0.z += v.z; cls0.w += v.w; }
        else if (lab == 1) { cls1.x += v.x; cls1.y += v.y; cls1.z += v.z; cls1.w += v.w; }
        else { cls2.x += v.x; cls2.y += v.y; cls2.z += v.z; cls2.w += v.w; }
    }
    red[0][tid] = cls0;
    red[1][tid] = cls1;
    red[2][tid] = cls2;
    if (tid < 32) atomicAdd(&scnt[labels[row0 + tid]], 1);   // LDS int: exact
    __syncthreads();

    if (tid < 128) {                     // d = tid; 8 contributors at k4=d>>2
        const int k4 = tid >> 2, comp = tid & 3;
        const float* rf = reinterpret_cast<const float*>(red);
        #pragma unroll
        for (int c = 0; c < 3; ++c) {
            float a = 0.f;
            #pragma unroll
            for (int w = 0; w < 8; ++w)
                a += rf[(c * 256 + k4 + 32 * w) * 4 + comp];
            Spart[((size_t)blk * 3 + c) * 128 + tid] = a;
        }
    }
    if (tid < 3) cntpart[blk * 4 + tid] = scnt[tid];
}

// ---- K2: deferred-exp pipeline, DMA triple buffer, counted vmcnt ----
// grid (64 itiles, NSPLIT); block 256 = 4 waves; wave owns 32 i-cols.
__global__ __launch_bounds__(256) void k2_stats(
        const __bf16* __restrict__ Ebf, const __bf16* __restrict__ Ebs,
        const int* __restrict__ labels, const float* __restrict__ nrm,
        float* __restrict__ part /*[NSPLIT][B]*/,
        const float* __restrict__ Spart, const int* __restrict__ cntpart,
        float* __restrict__ S /*[3*128]*/, float* __restrict__ counts /*[4]*/,
        u64* __restrict__ lossfix, u64* __restrict__ validfix,
        unsigned int* __restrict__ done) {
    __shared__ __bf16 Ab[3][4096];       // 24 KB A-tile TRIPLE buffer

    const int tid = threadIdx.x;
    const int lane = tid & 63;
    const int wave = tid >> 6;
    const int itile = blockIdx.x;        // 0..63 (128 i-cols per block)
    const int split = blockIdx.y;        // 0..NSPLIT-1
    const int col = lane & 31;
    const int icol = itile * 128 + wave * 32 + col;

    const float negm = -class_invtemp(labels[icol]) * LOG2E * nrm[icol];

    // B frag (i side), pre-scaled (Ebs), register-resident (32 VGPR)
    const int iT = itile * 4 + wave;
    const __bf16* bbase = Ebs + (size_t)iT * 4096 + lane * 8;
    bf16x8 Bf[8];
    #pragma unroll
    for (int c = 0; c < 8; ++c)
        Bf[c] = *reinterpret_cast<const bf16x8*>(bbase + c * 512);

    // A tiles (j side): Ebf tiles [split*NSTEPS, +NSTEPS), 8 KB each
    const __bf16* abase = Ebf + (size_t)split * NSTEPS * 4096;
    const int woff = wave * 1024 + lane * 8;     // per-lane global offset

    // prologue: DMA tiles 0 and 1 (4 ops in flight)
    load_lds16(abase + woff,              &Ab[0][wave * 1024]);
    load_lds16(abase + woff + 512,        &Ab[0][wave * 1024 + 512]);
    load_lds16(abase + 4096 + woff,       &Ab[1][wave * 1024]);
    load_lds16(abase + 4096 + woff + 512, &Ab[1][wave * 1024 + 512]);

    float Zacc[4];
    #pragma unroll
    for (int q = 0; q < 4; ++q) Zacc[q] = 0.f;

    floatx16 accA, accB;                 // even/odd acc generations (named)

    // per-tile body: MFMA tile t into cur, then exp tile t-1's prev.
    auto tile_body = [&](int t, floatx16& cur, floatx16& prev,
                         bool doExp, bool last) {
        if (!last) asm volatile("s_waitcnt vmcnt(2)" ::: "memory");
        else       asm volatile("s_waitcnt vmcnt(0)" ::: "memory");
        __builtin_amdgcn_s_barrier();            // raw: no implicit drain

        // issue DMA for tile t+2 (WAR-safe: buf last read at t-1, done
        // before the barrier all waves just crossed)
        if (t + 2 < NSTEPS) {
            const __bf16* g = abase + (size_t)(t + 2) * 4096 + woff;
            __bf16* l = &Ab[(t + 2) % 3][wave * 1024];
            load_lds16(g, l);
            load_lds16(g + 512, l + 512);
        }

        // ds_read current A fragments (conflict-free, lane-contiguous 16B)
        const __bf16* abuf = &Ab[t % 3][0];
        bf16x8 A[8];
        #pragma unroll
        for (int c = 0; c < 8; ++c)
            A[c] = *reinterpret_cast<const bf16x8*>(abuf + c * 512 + lane * 8);

        // single 8-deep MFMA chain into cur (latency hidden by prev-exp)
        #pragma unroll
        for (int r = 0; r < 16; ++r) cur[r] = 0.f;
        __builtin_amdgcn_s_setprio(1);
        #pragma unroll
        for (int c = 0; c < 8; ++c)
            cur = __builtin_amdgcn_mfma_f32_32x32x16_bf16(A[c], Bf[c], cur, 0, 0, 0);
        __builtin_amdgcn_s_setprio(0);

        // deferred exp of PREV tile's acc: no dep on cur -> runs on the
        // VALU/trans pipe while the matrix pipe crunches cur
        if (doExp) {
            #pragma unroll
            for (int q = 0; q < 4; ++q) {
                Zacc[q] += (__builtin_amdgcn_exp2f(prev[4 * q]     + negm)
                          + __builtin_amdgcn_exp2f(prev[4 * q + 1] + negm))
                         + (__builtin_amdgcn_exp2f(prev[4 * q + 2] + negm)
                          + __builtin_amdgcn_exp2f(prev[4 * q + 3] + negm));
            }
        }
    };

    tile_body(0, accA, accB, false, false);          // tile 0 -> accA
    #pragma unroll 1
    for (int t = 1; t <= NSTEPS - 3; t += 2) {       // t = 1,3,...,13
        tile_body(t,     accB, accA, true, false);   // odd  -> accB, exp accA
        tile_body(t + 1, accA, accB, true, false);   // even -> accA, exp accB
    }
    tile_body(NSTEPS - 1, accB, accA, true, true);   // tile 15 -> accB, exp accA
    // epilogue: exp last tile's acc (accB)
    #pragma unroll
    for (int q = 0; q < 4; ++q) {
        Zacc[q] += (__builtin_amdgcn_exp2f(accB[4 * q]     + negm)
                  + __builtin_amdgcn_exp2f(accB[4 * q + 1] + negm))
                 + (__builtin_amdgcn_exp2f(accB[4 * q + 2] + negm)
                  + __builtin_amdgcn_exp2f(accB[4 * q + 3] + negm));
    }

    float Zt = (Zacc[0] + Zacc[1]) + (Zacc[2] + Zacc[3]);
    Zt += __shfl_xor(Zt, 32);            // lanes l, l+32 hold same i-col
    if (lane < 32)
        part[(size_t)split * B_ROWS + icol] = Zt;

    // ---- aux (ordered before k3 by stream): S, counts, ticket zero ----
    if (split == 0) {
        if (itile < 3 && tid < 128) {
            float a = 0.f;
            #pragma unroll 8
            for (int g = 0; g < 256; ++g)
                a += Spart[((size_t)g * 3 + itile) * 128 + tid];
            S[itile * 128 + tid] = a;
        } else if (itile == 3 && tid < 3) {
            int a = 0;
            #pragma unroll 8
            for (int g = 0; g < 256; ++g) a += cntpart[g * 4 + tid];
            counts[tid] = (float)a;
        } else if (itile == 4 && tid == 0) {
            *lossfix = 0ull;
            *validfix = 0ull;
            *done = 0u;
        }
    }
}

// ---- K3: per-row loss (8 thr/row), fixed-point accumulate + ticket ----
__global__ __launch_bounds__(256) void k3_rowloss(
        const float* __restrict__ E, const int* __restrict__ labels,
        const float* __restrict__ S, const float* __restrict__ counts,
        const float* __restrict__ nrm, const float* __restrict__ part,
        u64* __restrict__ lossfix, u64* __restrict__ validfix,
        unsigned int* __restrict__ done, float* __restrict__ out) {
    __shared__ float sS[384];
    const int tid = threadIdx.x;
    if (tid < 128) {
        sS[tid]       = S[tid];
        sS[128 + tid] = S[128 + tid];
        sS[256 + tid] = S[256 + tid];
    }
    __syncthreads();

    const int r = tid >> 3, g = tid & 7;       // 32 rows/block, 8 thr/row
    const int i = blockIdx.x * 32 + r;
    const int lab = labels[i];
    const float invt = class_invtemp(lab);

    const float4* er = reinterpret_cast<const float4*>(E + (size_t)i * D_DIM);
    const float4* sr = reinterpret_cast<const float4*>(&sS[lab * 128]);
    float dotS = 0.f;
    #pragma unroll
    for (int q = 0; q < 4; ++q) {
        float4 v = er[g * 4 + q];
        float4 s = sr[g * 4 + q];
        dotS += v.x * s.x + v.y * s.y + v.z * s.z + v.w * s.w;
    }
    float Zp = 0.f;
    #pragma unroll
    for (int p = 0; p < NSPLIT / 8; ++p)
        Zp += part[(size_t)(g + p * 8) * B_ROWS + i];

    #pragma unroll
    for (int off = 1; off < 8; off <<= 1) {
        dotS += __shfl_xor(dotS, off);
        Zp   += __shfl_xor(Zp, off);
    }

    float loss = 0.f;
    int valid = 0;
    if (g == 0) {
        const float nr = nrm[i];
        const float C = counts[lab] - 1.0f;
        const float lse = invt * nr + LN2 * __builtin_amdgcn_logf(Zp);
        const float P_nat = invt * (dotS - nr);
        if (C > 0.f) {
            loss = -(BASE_TEMP * invt) * (P_nat - C * lse) / (C + 1e-8f);
            valid = 1;
        }
    }
    loss += __shfl_down(loss, 8);   valid += __shfl_down(valid, 8);
    loss += __shfl_down(loss, 16);  valid += __shfl_down(valid, 16);
    loss += __shfl_down(loss, 32);  valid += __shfl_down(valid, 32);

    __shared__ float rl[4];
    __shared__ int rv[4];
    if ((tid & 63) == 0) { rl[tid >> 6] = loss; rv[tid >> 6] = valid; }
    __syncthreads();
    if (tid == 0) {
        float bt = (rl[0] + rl[1]) + (rl[2] + rl[3]);
        int bv = (rv[0] + rv[1]) + (rv[2] + rv[3]);
        atomicAdd(lossfix, fix64(bt));
        atomicAdd(validfix, (u64)bv);
        __threadfence();
        unsigned int t = atomicAdd(done, 1u);
        if (t == gridDim.x - 1) {     // last block finalizes (deterministic)
            u64 L = atomicAdd(lossfix, 0ull);
            u64 V = atomicAdd(validfix, 0ull);
            double T = (double)(long long)L * (1.0 / (double)FIX_SCALE);
            double N = (double)(long long)V;
            out[0] = (N > 0.0) ? (float)(T / fmax(N, 1.0)) : 0.f;
        }
    }
}

extern "C" void kernel_launch(void* const* d_in, const int* in_sizes, int n_in,
                              void* d_out, int out_size, void* d_ws, size_t ws_size,
                              hipStream_t stream) {
    const float* E = (const float*)d_in[0];
    const int* labels = (const int*)d_in[1];
    float* out = (float*)d_out;
    char* ws = (char*)d_ws;

    // workspace layout (~6 MB)
    const size_t OFF_EBF   = 0;                        // 2 MB tiled bf16
    const size_t OFF_EBS   = (size_t)2 << 20;          // 2 MB tiled bf16 (scaled)
    const size_t OFF_NRM   = (size_t)4 << 20;          // 32 KB row norms
    const size_t OFF_SPART = OFF_NRM + 32768;          // 384 KB
    const size_t OFF_CNTP  = OFF_SPART + 393216;       // 4 KB
    const size_t OFF_S     = OFF_CNTP + 4096;          // 1.5 KB
    const size_t OFF_MISC  = OFF_S + 2048;             // counts + ticket
    const size_t OFF_PART  = (size_t)5 << 20;          // 512 KB (16 x 8192 f32)

    __bf16* Ebf = (__bf16*)(ws + OFF_EBF);
    __bf16* Ebs = (__bf16*)(ws + OFF_EBS);
    float* nrm = (float*)(ws + OFF_NRM);
    float* Spart = (float*)(ws + OFF_SPART);
    int* cntpart = (int*)(ws + OFF_CNTP);
    float* S = (float*)(ws + OFF_S);
    float* counts = (float*)(ws + OFF_MISC);           // 4 f32
    u64* lossfix = (u64*)(ws + OFF_MISC + 16);
    u64* validfix = (u64*)(ws + OFF_MISC + 24);
    unsigned int* done = (unsigned int*)(ws + OFF_MISC + 32);
    float* part = (float*)(ws + OFF_PART);

    k0_prep<<<256, 256, 0, stream>>>(E, labels, Ebf, Ebs, nrm, Spart, cntpart);
    k2_stats<<<dim3(64, NSPLIT), 256, 0, stream>>>(
        Ebf, Ebs, labels, nrm, part, Spart, cntpart, S, counts,
        lossfix, validfix, done);
    k3_rowloss<<<256, 256, 0, stream>>>(E, labels, S, counts, nrm, part,
                                        lossfix, validfix, done, out);
}

// Round 20
// 46.329 us; speedup vs baseline: 1.5748x; 1.0166x over previous
//
#include <hip/hip_runtime.h>
#include <hip/hip_bf16.h>

// ClassBalancedSupConLoss, B=8192, D=128.
// loss_i = -(BASE/t_i)*[P_i - C_i*lse_i]/(C_i+eps)
//   P_i   = invt_i*(e_i.S_{c(i)} - ||e_i||^2)      (fp32 closed form)
//   C_i   = count_{c(i)} - 1
//   lse_i = invt_i*||e_i||^2 + ln(Z_i),  Z_i = sum_j exp2(v_ij - m_i),
//           m_i = invt_i*log2e*||e_i||^2 (fixed reference; exact identity)
// r20: BARRIER-HALVING A/B. Robust invariant across r2-r19: k2 time ~
// (#barrier-steps) x ~2.2us, insensitive to step content. This round
// processes TWO j-tiles per barrier interval (8 intervals instead of 16
// steps): [vmcnt(0)] [s_barrier] [DMA next 2 tiles] [two independent
// 8-deep MFMA chains (ILP=2, r5/r11)] [exp both]. 4-buffer LDS rotation
// (32 KB -> still 4 blocks/CU). Hazards: vmcnt BEFORE barrier => all
// waves' current-tile DMA landed when any wave crosses (r18/r19-proven);
// DMA issue AFTER barrier => WAR-safe (buffers last read one interval
// ago, readers crossed this barrier).
// LESSONS kept: r8/r17 no min-waves launch_bounds (plain (256), ~110
// VGPR, A read in 4-chunk halves); r12 no persistent acc; r14 DMA
// staging; r15 no tail fusion.
// Ebf/Ebs in MFMA-fragment-tiled order (validated r4+):
//   (r,k) -> tile r>>5, chunk k>>4, lane (r&31)+((k>>3)&1)*32, e k&7.

#define B_ROWS 8192
#define D_DIM 128
#define NSPLIT 16
#define JRANGE (B_ROWS / NSPLIT)     // 512
#define NSTEPS (JRANGE / 32)         // 16 tiles
#define NINTERVALS (NSTEPS / 2)      // 8 barrier intervals
#define BASE_TEMP 0.07f
#define LOG2E 1.4426950408889634f
#define LN2 0.6931471805599453f
#define FIX_SCALE 1048576.0f         // 2^20

typedef __bf16 bf16x8 __attribute__((ext_vector_type(8)));
typedef __bf16 bf16x4 __attribute__((ext_vector_type(4)));
typedef float floatx16 __attribute__((ext_vector_type(16)));
typedef unsigned long long u64;

__device__ __forceinline__ float class_invtemp(int lbl) {
    return (lbl == 0) ? 12.5f : ((lbl == 1) ? 20.0f : 10.0f);
}

__device__ __forceinline__ u64 fix64(float v) {
    return (u64)(long long)llrintf(v * FIX_SCALE);
}

// direct global->LDS DMA, 16B per lane; lds base must be wave-uniform
__device__ __forceinline__ void load_lds16(const __bf16* g, __bf16* l) {
    __builtin_amdgcn_global_load_lds(
        (const __attribute__((address_space(1))) void*)g,
        (__attribute__((address_space(3))) void*)l,
        16, 0, 0);
}

// ---- K0: single-pass cast->tiled Ebf/Ebs + norms + class partials ----
__global__ __launch_bounds__(256) void k0_prep(
        const float* __restrict__ E, const int* __restrict__ labels,
        __bf16* __restrict__ Ebf, __bf16* __restrict__ Ebs,
        float* __restrict__ nrm,
        float* __restrict__ Spart /*[256][3][128]*/,
        int* __restrict__ cntpart /*[256][4]*/) {
    const int blk = blockIdx.x;          // 256 blocks x 32 rows
    const int tid = threadIdx.x;
    const int row0 = blk * 32;

    __shared__ float4 red[3][256];       // 12 KB class partial reduce
    __shared__ int scnt[3];
    if (tid < 3) scnt[tid] = 0;

    float4 cls0 = {0.f, 0.f, 0.f, 0.f};
    float4 cls1 = {0.f, 0.f, 0.f, 0.f};
    float4 cls2 = {0.f, 0.f, 0.f, 0.f};

    const float4* src = reinterpret_cast<const float4*>(E + (size_t)row0 * D_DIM);
    #pragma unroll
    for (int p = 0; p < 4; ++p) {
        int idx = p * 256 + tid;         // 1024 float4 = 32 rows x 32 k4
        float4 v = src[idx];
        int r = idx >> 5, k4 = idx & 31;
        int R = row0 + r;
        int lab = labels[R];
        float sc = class_invtemp(lab) * LOG2E;
        int T = R >> 5;
        int l = (R & 31) + ((k4 >> 1) & 1) * 32;
        int c = k4 >> 2;
        size_t dst = (size_t)T * 4096 + c * 512 + l * 8 + (k4 & 1) * 4;
        bf16x4 o  = { (__bf16)v.x, (__bf16)v.y, (__bf16)v.z, (__bf16)v.w };
        bf16x4 os = { (__bf16)(v.x * sc), (__bf16)(v.y * sc),
                      (__bf16)(v.z * sc), (__bf16)(v.w * sc) };
        *reinterpret_cast<bf16x4*>(Ebf + dst) = o;
        *reinterpret_cast<bf16x4*>(Ebs + dst) = os;
        // norms: 32 consecutive lanes hold one full row
        float s = v.x * v.x + v.y * v.y + v.z * v.z + v.w * v.w;
        s += __shfl_xor(s, 1);  s += __shfl_xor(s, 2);  s += __shfl_xor(s, 4);
        s += __shfl_xor(s, 8);  s += __shfl_xor(s, 16);
        if ((tid & 31) == 0) nrm[R] = s;
        // class partials in registers (thread owns dims [4*k4, 4*k4+4))
        if (lab == 0) { cls0.x += v.x; cls0.y += v.y; cls0.z += v.z; cls0.w += v.w; }
        else if (lab == 1) { cls1.x += v.x; cls1.y += v.y; cls1.z += v.z; cls1.w += v.w; }
        else { cls2.x += v.x; cls2.y += v.y; cls2.z += v.z; cls2.w += v.w; }
    }
    red[0][tid] = cls0;
    red[1][tid] = cls1;
    red[2][tid] = cls2;
    if (tid < 32) atomicAdd(&scnt[labels[row0 + tid]], 1);   // LDS int: exact
    __syncthreads();

    if (tid < 128) {                     // d = tid; 8 contributors at k4=d>>2
        const int k4 = tid >> 2, comp = tid & 3;
        const float* rf = reinterpret_cast<const float*>(red);
        #pragma unroll
        for (int c = 0; c < 3; ++c) {
            float a = 0.f;
            #pragma unroll
            for (int w = 0; w < 8; ++w)
                a += rf[(c * 256 + k4 + 32 * w) * 4 + comp];
            Spart[((size_t)blk * 3 + c) * 128 + tid] = a;
        }
    }
    if (tid < 3) cntpart[blk * 4 + tid] = scnt[tid];
}

// ---- K2: 2 tiles per barrier interval, 4-buffer DMA rotation ----
// grid (64 itiles, NSPLIT); block 256 = 4 waves; wave owns 32 i-cols.
__global__ __launch_bounds__(256) void k2_stats(
        const __bf16* __restrict__ Ebf, const __bf16* __restrict__ Ebs,
        const int* __restrict__ labels, const float* __restrict__ nrm,
        float* __restrict__ part /*[NSPLIT][B]*/,
        const float* __restrict__ Spart, const int* __restrict__ cntpart,
        float* __restrict__ S /*[3*128]*/, float* __restrict__ counts /*[4]*/,
        u64* __restrict__ lossfix, u64* __restrict__ validfix,
        unsigned int* __restrict__ done) {
    __shared__ __bf16 Ab[4][4096];       // 32 KB A-tile 4-buffer rotation

    const int tid = threadIdx.x;
    const int lane = tid & 63;
    const int wave = tid >> 6;
    const int itile = blockIdx.x;        // 0..63 (128 i-cols per block)
    const int split = blockIdx.y;        // 0..NSPLIT-1
    const int col = lane & 31;
    const int icol = itile * 128 + wave * 32 + col;

    const float negm = -class_invtemp(labels[icol]) * LOG2E * nrm[icol];

    // B frag (i side), pre-scaled (Ebs), register-resident (32 VGPR)
    const int iT = itile * 4 + wave;
    const __bf16* bbase = Ebs + (size_t)iT * 4096 + lane * 8;
    bf16x8 Bf[8];
    #pragma unroll
    for (int c = 0; c < 8; ++c)
        Bf[c] = *reinterpret_cast<const bf16x8*>(bbase + c * 512);

    // A tiles (j side): Ebf tiles [split*NSTEPS, +NSTEPS), 8 KB each
    const __bf16* abase = Ebf + (size_t)split * NSTEPS * 4096;
    const int woff = wave * 1024 + lane * 8;     // per-lane global offset

    // prologue: DMA tiles 0,1 into bufs 0,1
    load_lds16(abase + woff,              &Ab[0][wave * 1024]);
    load_lds16(abase + woff + 512,        &Ab[0][wave * 1024 + 512]);
    load_lds16(abase + 4096 + woff,       &Ab[1][wave * 1024]);
    load_lds16(abase + 4096 + woff + 512, &Ab[1][wave * 1024 + 512]);

    float Zacc[4];
    #pragma unroll
    for (int q = 0; q < 4; ++q) Zacc[q] = 0.f;

    #pragma unroll 1
    for (int iv = 0; iv < NINTERVALS; ++iv) {
        const int t0 = 2 * iv, t1 = 2 * iv + 1;

        // my current-tile DMA landed (issued one full interval ago);
        // BEFORE the barrier => when any wave crosses, ALL waves' landed
        asm volatile("s_waitcnt vmcnt(0)" ::: "memory");
        __builtin_amdgcn_s_barrier();

        // issue next interval's 2 tiles (WAR-safe: those bufs were last
        // read at interval iv-1; readers crossed the barrier above)
        if (t0 + 2 < NSTEPS) {
            const __bf16* g0 = abase + (size_t)(t0 + 2) * 4096 + woff;
            __bf16* l0 = &Ab[(t0 + 2) & 3][wave * 1024];
            load_lds16(g0, l0);
            load_lds16(g0 + 512, l0 + 512);
            const __bf16* g1 = abase + (size_t)(t1 + 2) * 4096 + woff;
            __bf16* l1 = &Ab[(t1 + 2) & 3][wave * 1024];
            load_lds16(g1, l1);
            load_lds16(g1 + 512, l1 + 512);
        }

        const __bf16* b0 = &Ab[t0 & 3][0];
        const __bf16* b1 = &Ab[t1 & 3][0];

        // two INDEPENDENT 8-deep chains (ILP=2), A read in 4-chunk halves
        // to cap register liveness (~110 VGPR total)
        floatx16 acc0, acc1;
        #pragma unroll
        for (int r = 0; r < 16; ++r) { acc0[r] = 0.f; acc1[r] = 0.f; }
        {
            bf16x8 A0[4], A1[4];
            #pragma unroll
            for (int c = 0; c < 4; ++c) {
                A0[c] = *reinterpret_cast<const bf16x8*>(b0 + c * 512 + lane * 8);
                A1[c] = *reinterpret_cast<const bf16x8*>(b1 + c * 512 + lane * 8);
            }
            #pragma unroll
            for (int c = 0; c < 4; ++c) {
                acc0 = __builtin_amdgcn_mfma_f32_32x32x16_bf16(A0[c], Bf[c], acc0, 0, 0, 0);
                acc1 = __builtin_amdgcn_mfma_f32_32x32x16_bf16(A1[c], Bf[c], acc1, 0, 0, 0);
            }
        }
        {
            bf16x8 A0[4], A1[4];
            #pragma unroll
            for (int c = 0; c < 4; ++c) {
                A0[c] = *reinterpret_cast<const bf16x8*>(b0 + (c + 4) * 512 + lane * 8);
                A1[c] = *reinterpret_cast<const bf16x8*>(b1 + (c + 4) * 512 + lane * 8);
            }
            #pragma unroll
            for (int c = 0; c < 4; ++c) {
                acc0 = __builtin_amdgcn_mfma_f32_32x32x16_bf16(A0[c], Bf[c + 4], acc0, 0, 0, 0);
                acc1 = __builtin_amdgcn_mfma_f32_32x32x16_bf16(A1[c], Bf[c + 4], acc1, 0, 0, 0);
            }
        }

        // exp both tiles (acc0's exps issue while acc1's chain drains)
        #pragma unroll
        for (int q = 0; q < 4; ++q) {
            Zacc[q] += (__builtin_amdgcn_exp2f(acc0[4 * q]     + negm)
                      + __builtin_amdgcn_exp2f(acc0[4 * q + 1] + negm))
                     + (__builtin_amdgcn_exp2f(acc0[4 * q + 2] + negm)
                      + __builtin_amdgcn_exp2f(acc0[4 * q + 3] + negm));
            Zacc[q] += (__builtin_amdgcn_exp2f(acc1[4 * q]     + negm)
                      + __builtin_amdgcn_exp2f(acc1[4 * q + 1] + negm))
                     + (__builtin_amdgcn_exp2f(acc1[4 * q + 2] + negm)
                      + __builtin_amdgcn_exp2f(acc1[4 * q + 3] + negm));
        }
        // no trailing barrier: next interval's barrier protects the
        // buffer rotation (nothing written this interval is read earlier)
    }

    float Zt = (Zacc[0] + Zacc[1]) + (Zacc[2] + Zacc[3]);
    Zt += __shfl_xor(Zt, 32);            // lanes l, l+32 hold same i-col
    if (lane < 32)
        part[(size_t)split * B_ROWS + icol] = Zt;

    // ---- aux (ordered before k3 by stream): S, counts, ticket zero ----
    if (split == 0) {
        if (itile < 3 && tid < 128) {
            float a = 0.f;
            #pragma unroll 8
            for (int g = 0; g < 256; ++g)
                a += Spart[((size_t)g * 3 + itile) * 128 + tid];
            S[itile * 128 + tid] = a;
        } else if (itile == 3 && tid < 3) {
            int a = 0;
            #pragma unroll 8
            for (int g = 0; g < 256; ++g) a += cntpart[g * 4 + tid];
            counts[tid] = (float)a;
        } else if (itile == 4 && tid == 0) {
            *lossfix = 0ull;
            *validfix = 0ull;
            *done = 0u;
        }
    }
}

// ---- K3: per-row loss (8 thr/row), fixed-point accumulate + ticket ----
__global__ __launch_bounds__(256) void k3_rowloss(
        const float* __restrict__ E, const int* __restrict__ labels,
        const float* __restrict__ S, const float* __restrict__ counts,
        const float* __restrict__ nrm, const float* __restrict__ part,
        u64* __restrict__ lossfix, u64* __restrict__ validfix,
        unsigned int* __restrict__ done, float* __restrict__ out) {
    __shared__ float sS[384];
    const int tid = threadIdx.x;
    if (tid < 128) {
        sS[tid]       = S[tid];
        sS[128 + tid] = S[128 + tid];
        sS[256 + tid] = S[256 + tid];
    }
    __syncthreads();

    const int r = tid >> 3, g = tid & 7;       // 32 rows/block, 8 thr/row
    const int i = blockIdx.x * 32 + r;
    const int lab = labels[i];
    const float invt = class_invtemp(lab);

    const float4* er = reinterpret_cast<const float4*>(E + (size_t)i * D_DIM);
    const float4* sr = reinterpret_cast<const float4*>(&sS[lab * 128]);
    float dotS = 0.f;
    #pragma unroll
    for (int q = 0; q < 4; ++q) {
        float4 v = er[g * 4 + q];
        float4 s = sr[g * 4 + q];
        dotS += v.x * s.x + v.y * s.y + v.z * s.z + v.w * s.w;
    }
    float Zp = 0.f;
    #pragma unroll
    for (int p = 0; p < NSPLIT / 8; ++p)
        Zp += part[(size_t)(g + p * 8) * B_ROWS + i];

    #pragma unroll
    for (int off = 1; off < 8; off <<= 1) {
        dotS += __shfl_xor(dotS, off);
        Zp   += __shfl_xor(Zp, off);
    }

    float loss = 0.f;
    int valid = 0;
    if (g == 0) {
        const float nr = nrm[i];
        const float C = counts[lab] - 1.0f;
        const float lse = invt * nr + LN2 * __builtin_amdgcn_logf(Zp);
        const float P_nat = invt * (dotS - nr);
        if (C > 0.f) {
            loss = -(BASE_TEMP * invt) * (P_nat - C * lse) / (C + 1e-8f);
            valid = 1;
        }
    }
    loss += __shfl_down(loss, 8);   valid += __shfl_down(valid, 8);
    loss += __shfl_down(loss, 16);  valid += __shfl_down(valid, 16);
    loss += __shfl_down(loss, 32);  valid += __shfl_down(valid, 32);

    __shared__ float rl[4];
    __shared__ int rv[4];
    if ((tid & 63) == 0) { rl[tid >> 6] = loss; rv[tid >> 6] = valid; }
    __syncthreads();
    if (tid == 0) {
        float bt = (rl[0] + rl[1]) + (rl[2] + rl[3]);
        int bv = (rv[0] + rv[1]) + (rv[2] + rv[3]);
        atomicAdd(lossfix, fix64(bt));
        atomicAdd(validfix, (u64)bv);
        __threadfence();
        unsigned int t = atomicAdd(done, 1u);
        if (t == gridDim.x - 1) {     // last block finalizes (deterministic)
            u64 L = atomicAdd(lossfix, 0ull);
            u64 V = atomicAdd(validfix, 0ull);
            double T = (double)(long long)L * (1.0 / (double)FIX_SCALE);
            double N = (double)(long long)V;
            out[0] = (N > 0.0) ? (float)(T / fmax(N, 1.0)) : 0.f;
        }
    }
}

extern "C" void kernel_launch(void* const* d_in, const int* in_sizes, int n_in,
                              void* d_out, int out_size, void* d_ws, size_t ws_size,
                              hipStream_t stream) {
    const float* E = (const float*)d_in[0];
    const int* labels = (const int*)d_in[1];
    float* out = (float*)d_out;
    char* ws = (char*)d_ws;

    // workspace layout (~6 MB)
    const size_t OFF_EBF   = 0;                        // 2 MB tiled bf16
    const size_t OFF_EBS   = (size_t)2 << 20;          // 2 MB tiled bf16 (scaled)
    const size_t OFF_NRM   = (size_t)4 << 20;          // 32 KB row norms
    const size_t OFF_SPART = OFF_NRM + 32768;          // 384 KB
    const size_t OFF_CNTP  = OFF_SPART + 393216;       // 4 KB
    const size_t OFF_S     = OFF_CNTP + 4096;          // 1.5 KB
    const size_t OFF_MISC  = OFF_S + 2048;             // counts + ticket
    const size_t OFF_PART  = (size_t)5 << 20;          // 512 KB (16 x 8192 f32)

    __bf16* Ebf = (__bf16*)(ws + OFF_EBF);
    __bf16* Ebs = (__bf16*)(ws + OFF_EBS);
    float* nrm = (float*)(ws + OFF_NRM);
    float* Spart = (float*)(ws + OFF_SPART);
    int* cntpart = (int*)(ws + OFF_CNTP);
    float* S = (float*)(ws + OFF_S);
    float* counts = (float*)(ws + OFF_MISC);           // 4 f32
    u64* lossfix = (u64*)(ws + OFF_MISC + 16);
    u64* validfix = (u64*)(ws + OFF_MISC + 24);
    unsigned int* done = (unsigned int*)(ws + OFF_MISC + 32);
    float* part = (float*)(ws + OFF_PART);

    k0_prep<<<256, 256, 0, stream>>>(E, labels, Ebf, Ebs, nrm, Spart, cntpart);
    k2_stats<<<dim3(64, NSPLIT), 256, 0, stream>>>(
        Ebf, Ebs, labels, nrm, part, Spart, cntpart, S, counts,
        lossfix, validfix, done);
    k3_rowloss<<<256, 256, 0, stream>>>(E, labels, S, counts, nrm, part,
                                        lossfix, validfix, done, out);
}

// Round 21
// 45.453 us; speedup vs baseline: 1.6052x; 1.0193x over previous
//
#include <hip/hip_runtime.h>
#include <hip/hip_bf16.h>

// ClassBalancedSupConLoss, B=8192, D=128.
// loss_i = -(BASE/t_i)*[P_i - C_i*lse_i]/(C_i+eps)
//   P_i   = invt_i*(e_i.S_{c(i)} - ||e_i||^2)      (fp32 closed form)
//   C_i   = count_{c(i)} - 1
//   lse_i = invt_i*||e_i||^2 + ln(Z_i),  Z_i = sum_j exp2(v_ij - m_i),
//           m_i = invt_i*log2e*||e_i||^2 (fixed reference; exact identity)
// r21: MAX-TLP A/B. Invariant found: MfmaUtil x dur ~ 6.5us in EVERY k2
// variant (the fixed MFMA-pipe work); the other ~80% is unhidden latency
// at 2-4 waves/SIMD. r14/r16's k2 body is exactly 64 VGPR (the 8-waves/
// SIMD boundary) and 16 KB LDS -- this round supplies the blocks to FILL
// that occupancy: NSPLIT 16->32 => grid (64,32)=2048 blocks = 8 blocks/CU
// (8x16KB = 128 <= 160KB LDS), 8 j-steps each. The syncthreads DMA-drain
// stall is now covered by the co-resident block's waves (m114 TLP).
// k2 body byte-identical to r14 (DMA staging, W=1 lean, dual K-split
// chains, persistent -m init).
// LESSONS kept: r8/r17 no min-waves launch_bounds; r12 no persistent acc;
// r10 prefetch load-bearing; r15 no tail fusion.
// Ebf/Ebs in MFMA-fragment-tiled order (validated r4+):
//   (r,k) -> tile r>>5, chunk k>>4, lane (r&31)+((k>>3)&1)*32, e k&7.

#define B_ROWS 8192
#define D_DIM 128
#define NSPLIT 32
#define JRANGE (B_ROWS / NSPLIT)     // 256
#define NSTEPS (JRANGE / 32)         // 8
#define BASE_TEMP 0.07f
#define LOG2E 1.4426950408889634f
#define LN2 0.6931471805599453f
#define FIX_SCALE 1048576.0f         // 2^20

typedef __bf16 bf16x8 __attribute__((ext_vector_type(8)));
typedef __bf16 bf16x4 __attribute__((ext_vector_type(4)));
typedef float floatx16 __attribute__((ext_vector_type(16)));
typedef unsigned long long u64;

__device__ __forceinline__ float class_invtemp(int lbl) {
    return (lbl == 0) ? 12.5f : ((lbl == 1) ? 20.0f : 10.0f);
}

__device__ __forceinline__ u64 fix64(float v) {
    return (u64)(long long)llrintf(v * FIX_SCALE);
}

// direct global->LDS DMA, 16B per lane; lds base must be wave-uniform
__device__ __forceinline__ void load_lds16(const __bf16* g, __bf16* l) {
    __builtin_amdgcn_global_load_lds(
        (const __attribute__((address_space(1))) void*)g,
        (__attribute__((address_space(3))) void*)l,
        16, 0, 0);
}

// ---- K0: single-pass cast->tiled Ebf/Ebs + norms + class partials ----
__global__ __launch_bounds__(256) void k0_prep(
        const float* __restrict__ E, const int* __restrict__ labels,
        __bf16* __restrict__ Ebf, __bf16* __restrict__ Ebs,
        float* __restrict__ nrm,
        float* __restrict__ Spart /*[256][3][128]*/,
        int* __restrict__ cntpart /*[256][4]*/) {
    const int blk = blockIdx.x;          // 256 blocks x 32 rows
    const int tid = threadIdx.x;
    const int row0 = blk * 32;

    __shared__ float4 red[3][256];       // 12 KB class partial reduce
    __shared__ int scnt[3];
    if (tid < 3) scnt[tid] = 0;

    float4 cls0 = {0.f, 0.f, 0.f, 0.f};
    float4 cls1 = {0.f, 0.f, 0.f, 0.f};
    float4 cls2 = {0.f, 0.f, 0.f, 0.f};

    const float4* src = reinterpret_cast<const float4*>(E + (size_t)row0 * D_DIM);
    #pragma unroll
    for (int p = 0; p < 4; ++p) {
        int idx = p * 256 + tid;         // 1024 float4 = 32 rows x 32 k4
        float4 v = src[idx];
        int r = idx >> 5, k4 = idx & 31;
        int R = row0 + r;
        int lab = labels[R];
        float sc = class_invtemp(lab) * LOG2E;
        int T = R >> 5;
        int l = (R & 31) + ((k4 >> 1) & 1) * 32;
        int c = k4 >> 2;
        size_t dst = (size_t)T * 4096 + c * 512 + l * 8 + (k4 & 1) * 4;
        bf16x4 o  = { (__bf16)v.x, (__bf16)v.y, (__bf16)v.z, (__bf16)v.w };
        bf16x4 os = { (__bf16)(v.x * sc), (__bf16)(v.y * sc),
                      (__bf16)(v.z * sc), (__bf16)(v.w * sc) };
        *reinterpret_cast<bf16x4*>(Ebf + dst) = o;
        *reinterpret_cast<bf16x4*>(Ebs + dst) = os;
        // norms: 32 consecutive lanes hold one full row
        float s = v.x * v.x + v.y * v.y + v.z * v.z + v.w * v.w;
        s += __shfl_xor(s, 1);  s += __shfl_xor(s, 2);  s += __shfl_xor(s, 4);
        s += __shfl_xor(s, 8);  s += __shfl_xor(s, 16);
        if ((tid & 31) == 0) nrm[R] = s;
        // class partials in registers (thread owns dims [4*k4, 4*k4+4))
        if (lab == 0) { cls0.x += v.x; cls0.y += v.y; cls0.z += v.z; cls0.w += v.w; }
        else if (lab == 1) { cls1.x += v.x; cls1.y += v.y; cls1.z += v.z; cls1.w += v.w; }
        else { cls2.x += v.x; cls2.y += v.y; cls2.z += v.z; cls2.w += v.w; }
    }
    red[0][tid] = cls0;
    red[1][tid] = cls1;
    red[2][tid] = cls2;
    if (tid < 32) atomicAdd(&scnt[labels[row0 + tid]], 1);   // LDS int: exact
    __syncthreads();

    if (tid < 128) {                     // d = tid; 8 contributors at k4=d>>2
        const int k4 = tid >> 2, comp = tid & 3;
        const float* rf = reinterpret_cast<const float*>(red);
        #pragma unroll
        for (int c = 0; c < 3; ++c) {
            float a = 0.f;
            #pragma unroll
            for (int w = 0; w < 8; ++w)
                a += rf[(c * 256 + k4 + 32 * w) * 4 + comp];
            Spart[((size_t)blk * 3 + c) * 128 + tid] = a;
        }
    }
    if (tid < 3) cntpart[blk * 4 + tid] = scnt[tid];
}

// ---- K2: r14 body, NSPLIT=32 -> 2048 blocks = 8 blocks/CU (max TLP) ----
// grid (64 itiles, 32 splits); block 256 = 4 waves; wave owns 32 i-cols.
__global__ __launch_bounds__(256) void k2_stats(
        const __bf16* __restrict__ Ebf, const __bf16* __restrict__ Ebs,
        const int* __restrict__ labels, const float* __restrict__ nrm,
        float* __restrict__ part /*[NSPLIT][B]*/,
        const float* __restrict__ Spart, const int* __restrict__ cntpart,
        float* __restrict__ S /*[3*128]*/, float* __restrict__ counts /*[4]*/,
        u64* __restrict__ lossfix, u64* __restrict__ validfix,
        unsigned int* __restrict__ done) {
    __shared__ __bf16 Ab[2][4096];       // 16 KB A-tile double buffer

    const int tid = threadIdx.x;
    const int lane = tid & 63;
    const int wave = tid >> 6;
    const int itile = blockIdx.x;        // 0..63 (128 i-cols per block)
    const int split = blockIdx.y;        // 0..31
    const int col = lane & 31;
    const int icol = itile * 128 + wave * 32 + col;

    const float negm = -class_invtemp(labels[icol]) * LOG2E * nrm[icol];

    // B frag (i side), pre-scaled (Ebs), register-resident (32 VGPR)
    const int iT = itile * 4 + wave;
    const __bf16* bbase = Ebs + (size_t)iT * 4096 + lane * 8;
    bf16x8 Bf[8];
    #pragma unroll
    for (int c = 0; c < 8; ++c)
        Bf[c] = *reinterpret_cast<const bf16x8*>(bbase + c * 512);

    // persistent C-in vector: a0 chain starts at -m with no per-step movs
    floatx16 init0;
    #pragma unroll
    for (int r = 0; r < 16; ++r) init0[r] = negm;

    // A tiles (j side): Ebf tiles [split*NSTEPS, +NSTEPS), 8 KB each
    const __bf16* abase = Ebf + (size_t)split * NSTEPS * 4096;
    const int woff = wave * 1024 + lane * 8;     // per-lane global offset

    // prologue: DMA tile 0 into buffer 0
    load_lds16(abase + woff,       &Ab[0][wave * 1024]);
    load_lds16(abase + woff + 512, &Ab[0][wave * 1024 + 512]);
    __syncthreads();                              // drains vmcnt(0)

    float Zacc[4];
    #pragma unroll
    for (int q = 0; q < 4; ++q) Zacc[q] = 0.f;

    for (int s = 0; s < NSTEPS; ++s) {
        // issue next-tile DMA FIRST (fire-and-forget; lands before barrier)
        if (s + 1 < NSTEPS) {
            const __bf16* g = abase + (size_t)(s + 1) * 4096 + woff;
            __bf16* l = &Ab[(s + 1) & 1][wave * 1024];
            load_lds16(g, l);
            load_lds16(g + 512, l + 512);
        }

        // ds_read current A fragments (conflict-free: lane-contiguous 16B)
        const __bf16* abuf = &Ab[s & 1][0];
        bf16x8 A[8];
        #pragma unroll
        for (int c = 0; c < 8; ++c)
            A[c] = *reinterpret_cast<const bf16x8*>(abuf + c * 512 + lane * 8);

        // dual K-split chains (depth 4 each): a0 = -m + dot(k<64), a1 = dot(k>=64)
        floatx16 a1;
        #pragma unroll
        for (int r = 0; r < 16; ++r) a1[r] = 0.f;
        floatx16 a0 = __builtin_amdgcn_mfma_f32_32x32x16_bf16(A[0], Bf[0], init0, 0, 0, 0);
        a1 = __builtin_amdgcn_mfma_f32_32x32x16_bf16(A[4], Bf[4], a1, 0, 0, 0);
        a0 = __builtin_amdgcn_mfma_f32_32x32x16_bf16(A[1], Bf[1], a0, 0, 0, 0);
        a1 = __builtin_amdgcn_mfma_f32_32x32x16_bf16(A[5], Bf[5], a1, 0, 0, 0);
        a0 = __builtin_amdgcn_mfma_f32_32x32x16_bf16(A[2], Bf[2], a0, 0, 0, 0);
        a1 = __builtin_amdgcn_mfma_f32_32x32x16_bf16(A[6], Bf[6], a1, 0, 0, 0);
        a0 = __builtin_amdgcn_mfma_f32_32x32x16_bf16(A[3], Bf[3], a0, 0, 0, 0);
        a1 = __builtin_amdgcn_mfma_f32_32x32x16_bf16(A[7], Bf[7], a1, 0, 0, 0);

        #pragma unroll
        for (int q = 0; q < 4; ++q) {
            Zacc[q] += (__builtin_amdgcn_exp2f(a0[4 * q]     + a1[4 * q])
                      + __builtin_amdgcn_exp2f(a0[4 * q + 1] + a1[4 * q + 1]))
                     + (__builtin_amdgcn_exp2f(a0[4 * q + 2] + a1[4 * q + 2])
                      + __builtin_amdgcn_exp2f(a0[4 * q + 3] + a1[4 * q + 3]));
        }

        // one barrier per step (compiler folds vmcnt/lgkm drain into it);
        // the drain stall is covered by the 7 other co-resident blocks
        __syncthreads();
    }

    float Zt = (Zacc[0] + Zacc[1]) + (Zacc[2] + Zacc[3]);
    Zt += __shfl_xor(Zt, 32);            // lanes l, l+32 hold same i-col
    if (lane < 32)
        part[(size_t)split * B_ROWS + icol] = Zt;

    // ---- aux (ordered before k3 by stream): S, counts, ticket zero ----
    if (split == 0) {
        if (itile < 3 && tid < 128) {
            float a = 0.f;
            #pragma unroll 8
            for (int g = 0; g < 256; ++g)
                a += Spart[((size_t)g * 3 + itile) * 128 + tid];
            S[itile * 128 + tid] = a;
        } else if (itile == 3 && tid < 3) {
            int a = 0;
            #pragma unroll 8
            for (int g = 0; g < 256; ++g) a += cntpart[g * 4 + tid];
            counts[tid] = (float)a;
        } else if (itile == 4 && tid == 0) {
            *lossfix = 0ull;
            *validfix = 0ull;
            *done = 0u;
        }
    }
}

// ---- K3: per-row loss (8 thr/row), fixed-point accumulate + ticket ----
__global__ __launch_bounds__(256) void k3_rowloss(
        const float* __restrict__ E, const int* __restrict__ labels,
        const float* __restrict__ S, const float* __restrict__ counts,
        const float* __restrict__ nrm, const float* __restrict__ part,
        u64* __restrict__ lossfix, u64* __restrict__ validfix,
        unsigned int* __restrict__ done, float* __restrict__ out) {
    __shared__ float sS[384];
    const int tid = threadIdx.x;
    if (tid < 128) {
        sS[tid]       = S[tid];
        sS[128 + tid] = S[128 + tid];
        sS[256 + tid] = S[256 + tid];
    }
    __syncthreads();

    const int r = tid >> 3, g = tid & 7;       // 32 rows/block, 8 thr/row
    const int i = blockIdx.x * 32 + r;
    const int lab = labels[i];
    const float invt = class_invtemp(lab);

    const float4* er = reinterpret_cast<const float4*>(E + (size_t)i * D_DIM);
    const float4* sr = reinterpret_cast<const float4*>(&sS[lab * 128]);
    float dotS = 0.f;
    #pragma unroll
    for (int q = 0; q < 4; ++q) {
        float4 v = er[g * 4 + q];
        float4 s = sr[g * 4 + q];
        dotS += v.x * s.x + v.y * s.y + v.z * s.z + v.w * s.w;
    }
    float Zp = 0.f;
    #pragma unroll
    for (int p = 0; p < NSPLIT / 8; ++p)
        Zp += part[(size_t)(g + p * 8) * B_ROWS + i];

    #pragma unroll
    for (int off = 1; off < 8; off <<= 1) {
        dotS += __shfl_xor(dotS, off);
        Zp   += __shfl_xor(Zp, off);
    }

    float loss = 0.f;
    int valid = 0;
    if (g == 0) {
        const float nr = nrm[i];
        const float C = counts[lab] - 1.0f;
        const float lse = invt * nr + LN2 * __builtin_amdgcn_logf(Zp);
        const float P_nat = invt * (dotS - nr);
        if (C > 0.f) {
            loss = -(BASE_TEMP * invt) * (P_nat - C * lse) / (C + 1e-8f);
            valid = 1;
        }
    }
    loss += __shfl_down(loss, 8);   valid += __shfl_down(valid, 8);
    loss += __shfl_down(loss, 16);  valid += __shfl_down(valid, 16);
    loss += __shfl_down(loss, 32);  valid += __shfl_down(valid, 32);

    __shared__ float rl[4];
    __shared__ int rv[4];
    if ((tid & 63) == 0) { rl[tid >> 6] = loss; rv[tid >> 6] = valid; }
    __syncthreads();
    if (tid == 0) {
        float bt = (rl[0] + rl[1]) + (rl[2] + rl[3]);
        int bv = (rv[0] + rv[1]) + (rv[2] + rv[3]);
        atomicAdd(lossfix, fix64(bt));
        atomicAdd(validfix, (u64)bv);
        __threadfence();
        unsigned int t = atomicAdd(done, 1u);
        if (t == gridDim.x - 1) {     // last block finalizes (deterministic)
            u64 L = atomicAdd(lossfix, 0ull);
            u64 V = atomicAdd(validfix, 0ull);
            double T = (double)(long long)L * (1.0 / (double)FIX_SCALE);
            double N = (double)(long long)V;
            out[0] = (N > 0.0) ? (float)(T / fmax(N, 1.0)) : 0.f;
        }
    }
}

extern "C" void kernel_launch(void* const* d_in, const int* in_sizes, int n_in,
                              void* d_out, int out_size, void* d_ws, size_t ws_size,
                              hipStream_t stream) {
    const float* E = (const float*)d_in[0];
    const int* labels = (const int*)d_in[1];
    float* out = (float*)d_out;
    char* ws = (char*)d_ws;

    // workspace layout (~6 MB)
    const size_t OFF_EBF   = 0;                        // 2 MB tiled bf16
    const size_t OFF_EBS   = (size_t)2 << 20;          // 2 MB tiled bf16 (scaled)
    const size_t OFF_NRM   = (size_t)4 << 20;          // 32 KB row norms
    const size_t OFF_SPART = OFF_NRM + 32768;          // 384 KB
    const size_t OFF_CNTP  = OFF_SPART + 393216;       // 4 KB
    const size_t OFF_S     = OFF_CNTP + 4096;          // 1.5 KB
    const size_t OFF_MISC  = OFF_S + 2048;             // counts + ticket
    const size_t OFF_PART  = (size_t)5 << 20;          // 1 MB (32 x 8192 f32)

    __bf16* Ebf = (__bf16*)(ws + OFF_EBF);
    __bf16* Ebs = (__bf16*)(ws + OFF_EBS);
    float* nrm = (float*)(ws + OFF_NRM);
    float* Spart = (float*)(ws + OFF_SPART);
    int* cntpart = (int*)(ws + OFF_CNTP);
    float* S = (float*)(ws + OFF_S);
    float* counts = (float*)(ws + OFF_MISC);           // 4 f32
    u64* lossfix = (u64*)(ws + OFF_MISC + 16);
    u64* validfix = (u64*)(ws + OFF_MISC + 24);
    unsigned int* done = (unsigned int*)(ws + OFF_MISC + 32);
    float* part = (float*)(ws + OFF_PART);

    k0_prep<<<256, 256, 0, stream>>>(E, labels, Ebf, Ebs, nrm, Spart, cntpart);
    k2_stats<<<dim3(64, NSPLIT), 256, 0, stream>>>(
        Ebf, Ebs, labels, nrm, part, Spart, cntpart, S, counts,
        lossfix, validfix, done);
    k3_rowloss<<<256, 256, 0, stream>>>(E, labels, S, counts, nrm, part,
                                        lossfix, validfix, done, out);
}